// Round 5
// baseline (37438.467 us; speedup 1.0000x reference)
//
#include <hip/hip_runtime.h>
#include <hip/hip_bf16.h>
#include <stdint.h>

typedef _Float16 f16;
typedef _Float16 f16x8 __attribute__((ext_vector_type(8)));
typedef float f32x4 __attribute__((ext_vector_type(4)));

#define LDF16X8(p) (*reinterpret_cast<const f16x8*>(p))

// ---------------- f32 -> f16 convert ----------------
__global__ __launch_bounds__(256) void k_cvt(const float* __restrict__ in,
                                             f16* __restrict__ out, int n) {
  int i = (blockIdx.x * 256 + threadIdx.x) * 4;
  if (i + 3 < n) {
    float4 v = *reinterpret_cast<const float4*>(in + i);
    out[i + 0] = (f16)v.x; out[i + 1] = (f16)v.y;
    out[i + 2] = (f16)v.z; out[i + 3] = (f16)v.w;
  } else {
    for (; i < n; ++i) out[i] = (f16)in[i];
  }
}

// ---------------- GEMM (M,K)x(N,K)^T + BN, f16 in, f16 out ----------------
// C[m,e] = BN_e( sum_k A[m,k]*B[e,k] )
// 128x128 tile, BK=32, 4 waves (2x2), each wave 64x64 via 4x4 16x16x32 MFMA.
// LDS layout k-block-major: elem(row,k) at ((k>>3)*128 + row)*8 + (k&7)
__global__ __launch_bounds__(256) void k_gemm_bn(
    const f16* __restrict__ A,    // (M,K)
    const f16* __restrict__ B,    // (N,K)
    const float* __restrict__ gamma, const float* __restrict__ beta,
    const float* __restrict__ mean, const float* __restrict__ var,
    f16* __restrict__ out,        // (M,N)
    int M, int N, int K) {
  __shared__ f16 Al[4 * 128 * 8];
  __shared__ f16 Bl[4 * 128 * 8];
  const int tid = threadIdx.x;
  const int lane = tid & 63, wid = tid >> 6;
  const int wm = wid >> 1, wn = wid & 1;
  const int row0 = blockIdx.x * 128, col0 = blockIdx.y * 128;

  f32x4 acc[4][4] = {};

  const int sR = tid >> 1;         // 0..127 staging row
  const int sk8 = (tid & 1) * 2;   // k8 block 0 or 2

  for (int k0 = 0; k0 < K; k0 += 32) {
    __syncthreads();
    {
      const f16* srcA = A + (size_t)(row0 + sR) * K + k0 + sk8 * 8;
      uint4 a0 = *reinterpret_cast<const uint4*>(srcA);
      uint4 a1 = *reinterpret_cast<const uint4*>(srcA + 8);
      *reinterpret_cast<uint4*>(&Al[(sk8 * 128 + sR) * 8]) = a0;
      *reinterpret_cast<uint4*>(&Al[((sk8 + 1) * 128 + sR) * 8]) = a1;
      const f16* srcB = B + (size_t)(col0 + sR) * K + k0 + sk8 * 8;
      uint4 b0 = *reinterpret_cast<const uint4*>(srcB);
      uint4 b1 = *reinterpret_cast<const uint4*>(srcB + 8);
      *reinterpret_cast<uint4*>(&Bl[(sk8 * 128 + sR) * 8]) = b0;
      *reinterpret_cast<uint4*>(&Bl[((sk8 + 1) * 128 + sR) * 8]) = b1;
    }
    __syncthreads();

    const int k8 = lane >> 4, r16 = lane & 15;
    f16x8 af[4], bfr[4];
#pragma unroll
    for (int m = 0; m < 4; ++m)
      af[m] = LDF16X8(&Al[(k8 * 128 + wm * 64 + m * 16 + r16) * 8]);
#pragma unroll
    for (int n = 0; n < 4; ++n)
      bfr[n] = LDF16X8(&Bl[(k8 * 128 + wn * 64 + n * 16 + r16) * 8]);
#pragma unroll
    for (int m = 0; m < 4; ++m)
#pragma unroll
      for (int n = 0; n < 4; ++n)
        acc[m][n] = __builtin_amdgcn_mfma_f32_16x16x32_f16(af[m], bfr[n], acc[m][n], 0, 0, 0);
  }

  // epilogue: BN per output column e, store f16
#pragma unroll
  for (int n = 0; n < 4; ++n) {
    int col = col0 + wn * 64 + n * 16 + (lane & 15);
    float g = gamma[col], be = beta[col], mu = mean[col], va = var[col];
    float s = g * rsqrtf(va + 1e-5f);
    float sh = be - mu * s;
#pragma unroll
    for (int m = 0; m < 4; ++m) {
#pragma unroll
      for (int r = 0; r < 4; ++r) {
        int row = row0 + wm * 64 + m * 16 + (lane >> 4) * 4 + r;
        out[(size_t)row * N + col] = (f16)(acc[m][n][r] * s + sh);
      }
    }
  }
}

// ---------------- persistent LiGRU scan (one launch per layer) ----------------
// 128 wgs x 256 thr. wg owns j-cols [j0, j0+8): a-rows U[j0..j0+7], z-rows U[1024+j0..].
// U slice in LDS f16, layout ((k>>3)*16 + e)*8 + (k&7). h published f16, double buffered.
// waves: (mt = wid&1) -> batch rows 16mt.. ; (kh = wid>>1) -> k half.
// Grid sync: all-to-all flag barrier; explicit __threadfence() both sides so the
// ordinary hpub loads/stores are agent-coherent across XCDs (L1 invalidate + L2 wb).
__global__ __launch_bounds__(256) void k_scan(
    const float* __restrict__ U,   // (2048,1024) f32
    const f16* __restrict__ w,     // (16384,2048) f16 BN'd gates input
    f16* __restrict__ hpub,        // [2][32][1024] f16
    f16* __restrict__ xoutH,       // (16384,1024) f16 (if !last)
    float* __restrict__ xoutF,     // (16384,1024) f32 (if last)
    float* __restrict__ hh,        // (32,3,1024) f32
    unsigned* __restrict__ flags,  // [128][32] uints (128B stride per wg)
    int layer, int last, int nwg) {
  __shared__ f16 Ul[16 * 1024];
  __shared__ float gl[2][32][16];

  const int tid = threadIdx.x;
  const int lane = tid & 63, wid = tid >> 6;
  const int mt = wid & 1, kh = wid >> 1;
  const int j0 = blockIdx.x * 8;

  // stage U slice -> LDS (f32 -> f16)
  for (int i = tid; i < 16 * 1024; i += 256) {
    int e = i >> 10, k = i & 1023;
    int erow = (e < 8) ? (j0 + e) : (1024 + j0 + e - 8);
    Ul[((k >> 3) * 16 + e) * 8 + (k & 7)] = (f16)U[(size_t)erow * 1024 + k];
  }
  __syncthreads();

  const int cb = tid >> 3;  // combine: batch 0..31
  const int cj = tid & 7;   // combine: j 0..7
  float hreg = 0.f;         // exact f32 h for this thread's (cb, j0+cj)

  const int r16 = lane & 15, kg4 = lane >> 4;

  // prefetch w for t=0
  float wa = (float)w[(size_t)(cb * 512) * 2048 + j0 + cj];
  float wz = (float)w[(size_t)(cb * 512) * 2048 + 1024 + j0 + cj];

  for (int t = 0; t < 512; ++t) {
    const int cur = t & 1, nxt = cur ^ 1;

    // ---- matvec slice: gates[b, e_local] partial over this wave's k-half ----
    f32x4 acc = {};
    const f16* hbase = hpub + cur * 32768 + (size_t)(mt * 16 + r16) * 1024 + kh * 512 + kg4 * 8;
#pragma unroll
    for (int kk = 0; kk < 16; ++kk) {
      f16x8 a = LDF16X8(hbase + kk * 32);
      f16x8 b = LDF16X8(&Ul[((kh * 64 + kk * 4 + kg4) * 16 + r16) * 8]);
      acc = __builtin_amdgcn_mfma_f32_16x16x32_f16(a, b, acc, 0, 0, 0);
    }
#pragma unroll
    for (int r = 0; r < 4; ++r)
      gl[kh][mt * 16 + kg4 * 4 + r][r16] = acc[r];
    __syncthreads();

    // ---- combine: one (b,j) element per thread ----
    {
      float apre = gl[0][cb][cj] + gl[1][cb][cj] + wa;
      float zpre = gl[0][cb][8 + cj] + gl[1][cb][8 + cj] + wz;
      float z = 1.f / (1.f + expf(-zpre));
      float hn = z * hreg + (1.f - z) * fmaxf(apre, 0.f);
      hreg = hn;
      hpub[nxt * 32768 + cb * 1024 + j0 + cj] = (f16)hn;
      size_t xoff = (size_t)(cb * 512 + t) * 1024 + j0 + cj;
      if (last) xoutF[xoff] = hn;
      else      xoutH[xoff] = (f16)hn;
      if (t == 511) hh[(size_t)(cb * 3 + layer) * 1024 + j0 + cj] = hn;
    }

    // ---- prefetch next step's w before the barrier spin ----
    if (t + 1 < 512) {
      size_t wrow = (size_t)(cb * 512 + t + 1) * 2048;
      wa = (float)w[wrow + j0 + cj];
      wz = (float)w[wrow + 1024 + j0 + cj];
    }

    // ---- all-to-all flag grid barrier (release/acquire + explicit fences) ----
    __syncthreads();      // all lanes done: gl reads, hpub/x writes issued
    __threadfence();      // release: make this wg's hpub stores agent-visible (L2 wb)
    if (tid == 0)
      __hip_atomic_store(&flags[(size_t)blockIdx.x * 32], (unsigned)(t + 1),
                         __ATOMIC_RELEASE, __HIP_MEMORY_SCOPE_AGENT);
    if (tid < 128) {  // 2 waves poll one flag each
      while (__hip_atomic_load(&flags[(size_t)tid * 32], __ATOMIC_ACQUIRE,
                               __HIP_MEMORY_SCOPE_AGENT) < (unsigned)(t + 1))
        __builtin_amdgcn_s_sleep(1);
    }
    __syncthreads();
    __threadfence();      // acquire: invalidate L1 so next hpub reads are fresh
  }
}

// ---------------- launcher ----------------
extern "C" void kernel_launch(void* const* d_in, const int* in_sizes, int n_in,
                              void* d_out, int out_size, void* d_ws, size_t ws_size,
                              hipStream_t stream) {
  const float* x     = (const float*)d_in[0];
  const float* W     = (const float*)d_in[1];
  const float* U     = (const float*)d_in[2];
  const float* gamma = (const float*)d_in[3];
  const float* beta  = (const float*)d_in[4];
  const float* rmean = (const float*)d_in[5];
  const float* rvar  = (const float*)d_in[6];
  float* outX  = (float*)d_out;                       // (32,512,1024) f32
  float* outHH = outX + (size_t)32 * 512 * 1024;      // (32,3,1024)  f32

  // Inter-layer f16 activations live in the d_out outX region (33.5 MB of 67 MB):
  // dead by the time the last layer's scan overwrites it with f32 output.
  f16* xb = (f16*)d_out;

  char* ws = (char*)d_ws;
  f16* wbuf = (f16*)(ws);                 // 16384*2048*2 = 67,108,864 B
  f16* Wb   = (f16*)(ws + 67108864);      //  2048*1024*2 =  4,194,304 B
  f16* hpub = (f16*)(ws + 71303168);      //  2*32*1024*2 =    131,072 B
  unsigned* flags = (unsigned*)(ws + 71434240);  // 128*32*4 = 16,384 B
  // total d_ws usage: ~71.5 MB

  // x -> f16
  k_cvt<<<16384, 256, 0, stream>>>(x, xb, 16777216);

  for (int l = 0; l < 3; ++l) {
    // W[l] -> f16
    k_cvt<<<2048, 256, 0, stream>>>(W + (size_t)l * 2097152, Wb, 2097152);
    // w = BN(x_l @ W^T)
    k_gemm_bn<<<dim3(128, 16), 256, 0, stream>>>(
        xb, Wb, gamma + l * 2048, beta + l * 2048, rmean + l * 2048, rvar + l * 2048,
        wbuf, 16384, 2048, 1024);
    // reset h and flags, then scan
    hipMemsetAsync(hpub, 0, 131072, stream);
    hipMemsetAsync(flags, 0, 16384, stream);
    k_scan<<<128, 256, 0, stream>>>(
        U + (size_t)l * 2097152, wbuf, hpub,
        xb, outX, outHH, flags, l, (l == 2) ? 1 : 0, 128);
  }
}

// Round 6
// 10200.784 us; speedup vs baseline: 3.6702x; 3.6702x over previous
//
#include <hip/hip_runtime.h>
#include <hip/hip_bf16.h>
#include <stdint.h>

typedef _Float16 f16;
typedef _Float16 f16x8 __attribute__((ext_vector_type(8)));
typedef float f32x4 __attribute__((ext_vector_type(4)));

#define LDF16X8(p) (*reinterpret_cast<const f16x8*>(p))

// ---------------- f32 -> f16 convert ----------------
__global__ __launch_bounds__(256) void k_cvt(const float* __restrict__ in,
                                             f16* __restrict__ out, int n) {
  int i = (blockIdx.x * 256 + threadIdx.x) * 4;
  if (i + 3 < n) {
    float4 v = *reinterpret_cast<const float4*>(in + i);
    out[i + 0] = (f16)v.x; out[i + 1] = (f16)v.y;
    out[i + 2] = (f16)v.z; out[i + 3] = (f16)v.w;
  } else {
    for (; i < n; ++i) out[i] = (f16)in[i];
  }
}

// ---------------- GEMM (M,K)x(N,K)^T + BN, f16 in, f16 out ----------------
__global__ __launch_bounds__(256) void k_gemm_bn(
    const f16* __restrict__ A,    // (M,K)
    const f16* __restrict__ B,    // (N,K)
    const float* __restrict__ gamma, const float* __restrict__ beta,
    const float* __restrict__ mean, const float* __restrict__ var,
    f16* __restrict__ out,        // (M,N)
    int M, int N, int K) {
  __shared__ f16 Al[4 * 128 * 8];
  __shared__ f16 Bl[4 * 128 * 8];
  const int tid = threadIdx.x;
  const int lane = tid & 63, wid = tid >> 6;
  const int wm = wid >> 1, wn = wid & 1;
  const int row0 = blockIdx.x * 128, col0 = blockIdx.y * 128;

  f32x4 acc[4][4] = {};

  const int sR = tid >> 1;         // 0..127 staging row
  const int sk8 = (tid & 1) * 2;   // k8 block 0 or 2

  for (int k0 = 0; k0 < K; k0 += 32) {
    __syncthreads();
    {
      const f16* srcA = A + (size_t)(row0 + sR) * K + k0 + sk8 * 8;
      uint4 a0 = *reinterpret_cast<const uint4*>(srcA);
      uint4 a1 = *reinterpret_cast<const uint4*>(srcA + 8);
      *reinterpret_cast<uint4*>(&Al[(sk8 * 128 + sR) * 8]) = a0;
      *reinterpret_cast<uint4*>(&Al[((sk8 + 1) * 128 + sR) * 8]) = a1;
      const f16* srcB = B + (size_t)(col0 + sR) * K + k0 + sk8 * 8;
      uint4 b0 = *reinterpret_cast<const uint4*>(srcB);
      uint4 b1 = *reinterpret_cast<const uint4*>(srcB + 8);
      *reinterpret_cast<uint4*>(&Bl[(sk8 * 128 + sR) * 8]) = b0;
      *reinterpret_cast<uint4*>(&Bl[((sk8 + 1) * 128 + sR) * 8]) = b1;
    }
    __syncthreads();

    const int k8 = lane >> 4, r16 = lane & 15;
    f16x8 af[4], bfr[4];
#pragma unroll
    for (int m = 0; m < 4; ++m)
      af[m] = LDF16X8(&Al[(k8 * 128 + wm * 64 + m * 16 + r16) * 8]);
#pragma unroll
    for (int n = 0; n < 4; ++n)
      bfr[n] = LDF16X8(&Bl[(k8 * 128 + wn * 64 + n * 16 + r16) * 8]);
#pragma unroll
    for (int m = 0; m < 4; ++m)
#pragma unroll
      for (int n = 0; n < 4; ++n)
        acc[m][n] = __builtin_amdgcn_mfma_f32_16x16x32_f16(af[m], bfr[n], acc[m][n], 0, 0, 0);
  }

  // epilogue: BN per output column e, store f16
#pragma unroll
  for (int n = 0; n < 4; ++n) {
    int col = col0 + wn * 64 + n * 16 + (lane & 15);
    float g = gamma[col], be = beta[col], mu = mean[col], va = var[col];
    float s = g * rsqrtf(va + 1e-5f);
    float sh = be - mu * s;
#pragma unroll
    for (int m = 0; m < 4; ++m) {
#pragma unroll
      for (int r = 0; r < 4; ++r) {
        int row = row0 + wm * 64 + m * 16 + (lane >> 4) * 4 + r;
        out[(size_t)row * N + col] = (f16)(acc[m][n][r] * s + sh);
      }
    }
  }
}

// ---------------- persistent LiGRU scan (one launch per layer) ----------------
// 128 wgs x 256 thr. wg owns j-cols [j0, j0+8). U slice in LDS f16.
// Grid sync per step: all-to-all flag barrier.
//  release: ONE agent release-fence (tid0, after syncthreads drained stores to L2)
//           + relaxed agent flag store (L2-bypass, lands at coherence point).
//  spin:    wave0 only, RELAXED agent loads (no cache-op per iteration).
//  acquire: ONE agent acquire-fence by wave0 after spin, then syncthreads.
__global__ __launch_bounds__(256) void k_scan(
    const float* __restrict__ U,   // (2048,1024) f32
    const f16* __restrict__ w,     // (16384,2048) f16 BN'd gates input
    f16* __restrict__ hpub,        // [2][32][1024] f16
    f16* __restrict__ xoutH,       // (16384,1024) f16 (if !last)
    float* __restrict__ xoutF,     // (16384,1024) f32 (if last)
    float* __restrict__ hh,        // (32,3,1024) f32
    unsigned* __restrict__ flags,  // [128][32] uints (128B stride per wg)
    int layer, int last, int nwg) {
  __shared__ f16 Ul[16 * 1024];
  __shared__ float gl[2][32][16];

  const int tid = threadIdx.x;
  const int lane = tid & 63, wid = tid >> 6;
  const int mt = wid & 1, kh = wid >> 1;
  const int j0 = blockIdx.x * 8;

  // stage U slice -> LDS (f32 -> f16)
  for (int i = tid; i < 16 * 1024; i += 256) {
    int e = i >> 10, k = i & 1023;
    int erow = (e < 8) ? (j0 + e) : (1024 + j0 + e - 8);
    Ul[((k >> 3) * 16 + e) * 8 + (k & 7)] = (f16)U[(size_t)erow * 1024 + k];
  }
  __syncthreads();

  const int cb = tid >> 3;  // combine: batch 0..31
  const int cj = tid & 7;   // combine: j 0..7
  float hreg = 0.f;         // exact f32 h for this thread's (cb, j0+cj)

  const int r16 = lane & 15, kg4 = lane >> 4;

  // prefetch w for t=0
  float wa = (float)w[(size_t)(cb * 512) * 2048 + j0 + cj];
  float wz = (float)w[(size_t)(cb * 512) * 2048 + 1024 + j0 + cj];

  for (int t = 0; t < 512; ++t) {
    const int cur = t & 1, nxt = cur ^ 1;

    // ---- matvec slice: gates[b, e_local] partial over this wave's k-half ----
    f32x4 acc = {};
    const f16* hbase = hpub + cur * 32768 + (size_t)(mt * 16 + r16) * 1024 + kh * 512 + kg4 * 8;
#pragma unroll
    for (int kk = 0; kk < 16; ++kk) {
      f16x8 a = LDF16X8(hbase + kk * 32);
      f16x8 b = LDF16X8(&Ul[((kh * 64 + kk * 4 + kg4) * 16 + r16) * 8]);
      acc = __builtin_amdgcn_mfma_f32_16x16x32_f16(a, b, acc, 0, 0, 0);
    }
#pragma unroll
    for (int r = 0; r < 4; ++r)
      gl[kh][mt * 16 + kg4 * 4 + r][r16] = acc[r];
    __syncthreads();

    // ---- combine: one (b,j) element per thread ----
    {
      float apre = gl[0][cb][cj] + gl[1][cb][cj] + wa;
      float zpre = gl[0][cb][8 + cj] + gl[1][cb][8 + cj] + wz;
      float z = 1.f / (1.f + expf(-zpre));
      float hn = z * hreg + (1.f - z) * fmaxf(apre, 0.f);
      hreg = hn;
      hpub[nxt * 32768 + cb * 1024 + j0 + cj] = (f16)hn;
      size_t xoff = (size_t)(cb * 512 + t) * 1024 + j0 + cj;
      if (last) xoutF[xoff] = hn;
      else      xoutH[xoff] = (f16)hn;
      if (t == 511) hh[(size_t)(cb * 3 + layer) * 1024 + j0 + cj] = hn;
    }

    // ---- prefetch next step's w before the barrier ----
    if (t + 1 < 512) {
      size_t wrow = (size_t)(cb * 512 + t + 1) * 2048;
      wa = (float)w[wrow + j0 + cj];
      wz = (float)w[wrow + 1024 + j0 + cj];
    }

    // ---- grid barrier: 1 release fence + relaxed store; wave0 relaxed spin; 1 acquire fence ----
    __syncthreads();   // all waves' hpub/x stores drained to L2 (vmcnt(0) before s_barrier)
    if (tid == 0) {
      __builtin_amdgcn_fence(__ATOMIC_RELEASE, "agent");   // wbl2: our stores -> L3
      __hip_atomic_store(&flags[(size_t)blockIdx.x * 32], (unsigned)(t + 1),
                         __ATOMIC_RELAXED, __HIP_MEMORY_SCOPE_AGENT);
    }
    if (tid < 64) {  // wave0: each lane polls 2 flags, relaxed (no cache ops)
      while (__hip_atomic_load(&flags[(size_t)tid * 32], __ATOMIC_RELAXED,
                               __HIP_MEMORY_SCOPE_AGENT) < (unsigned)(t + 1))
        __builtin_amdgcn_s_sleep(1);
      while (__hip_atomic_load(&flags[(size_t)(64 + tid) * 32], __ATOMIC_RELAXED,
                               __HIP_MEMORY_SCOPE_AGENT) < (unsigned)(t + 1))
        __builtin_amdgcn_s_sleep(1);
      __builtin_amdgcn_fence(__ATOMIC_ACQUIRE, "agent");   // inv L1/L2 once
    }
    __syncthreads();
  }
}

// ---------------- launcher ----------------
extern "C" void kernel_launch(void* const* d_in, const int* in_sizes, int n_in,
                              void* d_out, int out_size, void* d_ws, size_t ws_size,
                              hipStream_t stream) {
  const float* x     = (const float*)d_in[0];
  const float* W     = (const float*)d_in[1];
  const float* U     = (const float*)d_in[2];
  const float* gamma = (const float*)d_in[3];
  const float* beta  = (const float*)d_in[4];
  const float* rmean = (const float*)d_in[5];
  const float* rvar  = (const float*)d_in[6];
  float* outX  = (float*)d_out;                       // (32,512,1024) f32
  float* outHH = outX + (size_t)32 * 512 * 1024;      // (32,3,1024)  f32

  // Inter-layer f16 activations live in the d_out outX region (33.5 MB of 67 MB):
  // dead by the time the last layer's scan overwrites it with f32 output.
  f16* xb = (f16*)d_out;

  char* ws = (char*)d_ws;
  f16* wbuf = (f16*)(ws);                 // 16384*2048*2 = 67,108,864 B
  f16* Wb   = (f16*)(ws + 67108864);      //  2048*1024*2 =  4,194,304 B
  f16* hpub = (f16*)(ws + 71303168);      //  2*32*1024*2 =    131,072 B
  unsigned* flags = (unsigned*)(ws + 71434240);  // 128*32*4 = 16,384 B
  // total d_ws usage: ~71.5 MB

  // x -> f16
  k_cvt<<<16384, 256, 0, stream>>>(x, xb, 16777216);

  for (int l = 0; l < 3; ++l) {
    // W[l] -> f16
    k_cvt<<<2048, 256, 0, stream>>>(W + (size_t)l * 2097152, Wb, 2097152);
    // w = BN(x_l @ W^T)
    k_gemm_bn<<<dim3(128, 16), 256, 0, stream>>>(
        xb, Wb, gamma + l * 2048, beta + l * 2048, rmean + l * 2048, rvar + l * 2048,
        wbuf, 16384, 2048, 1024);
    // reset h and flags, then scan
    hipMemsetAsync(hpub, 0, 131072, stream);
    hipMemsetAsync(flags, 0, 16384, stream);
    k_scan<<<128, 256, 0, stream>>>(
        U + (size_t)l * 2097152, wbuf, hpub,
        xb, outX, outHH, flags, l, (l == 2) ? 1 : 0, 128);
  }
}

// Round 10
// 9618.382 us; speedup vs baseline: 3.8924x; 1.0606x over previous
//
#include <hip/hip_runtime.h>
#include <hip/hip_bf16.h>
#include <stdint.h>

typedef _Float16 f16;
typedef _Float16 f16x8 __attribute__((ext_vector_type(8)));
typedef float f32x4 __attribute__((ext_vector_type(4)));
typedef unsigned long long u64;

#define LDF16X8(p) (*reinterpret_cast<const f16x8*>(p))

// coherent (agent-scope, L2-bypass) 16B h load as 2x8B relaxed atomics
__device__ __forceinline__ f16x8 ld_h(const f16* p) {
  union { u64 q[2]; f16x8 v; } u;
  u.q[0] = __hip_atomic_load((const u64*)p,     __ATOMIC_RELAXED, __HIP_MEMORY_SCOPE_AGENT);
  u.q[1] = __hip_atomic_load((const u64*)p + 1, __ATOMIC_RELAXED, __HIP_MEMORY_SCOPE_AGENT);
  return u.v;
}

// ---------------- f32 -> f16 convert ----------------
__global__ __launch_bounds__(256) void k_cvt(const float* __restrict__ in,
                                             f16* __restrict__ out, int n) {
  int i = (blockIdx.x * 256 + threadIdx.x) * 4;
  if (i + 3 < n) {
    float4 v = *reinterpret_cast<const float4*>(in + i);
    out[i + 0] = (f16)v.x; out[i + 1] = (f16)v.y;
    out[i + 2] = (f16)v.z; out[i + 3] = (f16)v.w;
  } else {
    for (; i < n; ++i) out[i] = (f16)in[i];
  }
}

// ---------------- GEMM (M,K)x(N,K)^T + BN, f16 in, f16 out ----------------
__global__ __launch_bounds__(256) void k_gemm_bn(
    const f16* __restrict__ A,    // (M,K)
    const f16* __restrict__ B,    // (N,K)
    const float* __restrict__ gamma, const float* __restrict__ beta,
    const float* __restrict__ mean, const float* __restrict__ var,
    f16* __restrict__ out,        // (M,N)
    int M, int N, int K) {
  __shared__ f16 Al[4 * 128 * 8];
  __shared__ f16 Bl[4 * 128 * 8];
  const int tid = threadIdx.x;
  const int lane = tid & 63, wid = tid >> 6;
  const int wm = wid >> 1, wn = wid & 1;
  const int row0 = blockIdx.x * 128, col0 = blockIdx.y * 128;

  f32x4 acc[4][4] = {};

  const int sR = tid >> 1;         // 0..127 staging row
  const int sk8 = (tid & 1) * 2;   // k8 block 0 or 2

  for (int k0 = 0; k0 < K; k0 += 32) {
    __syncthreads();
    {
      const f16* srcA = A + (size_t)(row0 + sR) * K + k0 + sk8 * 8;
      uint4 a0 = *reinterpret_cast<const uint4*>(srcA);
      uint4 a1 = *reinterpret_cast<const uint4*>(srcA + 8);
      *reinterpret_cast<uint4*>(&Al[(sk8 * 128 + sR) * 8]) = a0;
      *reinterpret_cast<uint4*>(&Al[((sk8 + 1) * 128 + sR) * 8]) = a1;
      const f16* srcB = B + (size_t)(col0 + sR) * K + k0 + sk8 * 8;
      uint4 b0 = *reinterpret_cast<const uint4*>(srcB);
      uint4 b1 = *reinterpret_cast<const uint4*>(srcB + 8);
      *reinterpret_cast<uint4*>(&Bl[(sk8 * 128 + sR) * 8]) = b0;
      *reinterpret_cast<uint4*>(&Bl[((sk8 + 1) * 128 + sR) * 8]) = b1;
    }
    __syncthreads();

    const int k8 = lane >> 4, r16 = lane & 15;
    f16x8 af[4], bfr[4];
#pragma unroll
    for (int m = 0; m < 4; ++m)
      af[m] = LDF16X8(&Al[(k8 * 128 + wm * 64 + m * 16 + r16) * 8]);
#pragma unroll
    for (int n = 0; n < 4; ++n)
      bfr[n] = LDF16X8(&Bl[(k8 * 128 + wn * 64 + n * 16 + r16) * 8]);
#pragma unroll
    for (int m = 0; m < 4; ++m)
#pragma unroll
      for (int n = 0; n < 4; ++n)
        acc[m][n] = __builtin_amdgcn_mfma_f32_16x16x32_f16(af[m], bfr[n], acc[m][n], 0, 0, 0);
  }

  // epilogue: BN per output column e, store f16
#pragma unroll
  for (int n = 0; n < 4; ++n) {
    int col = col0 + wn * 64 + n * 16 + (lane & 15);
    float g = gamma[col], be = beta[col], mu = mean[col], va = var[col];
    float s = g * rsqrtf(va + 1e-5f);
    float sh = be - mu * s;
#pragma unroll
    for (int m = 0; m < 4; ++m) {
#pragma unroll
      for (int r = 0; r < 4; ++r) {
        int row = row0 + wm * 64 + m * 16 + (lane >> 4) * 4 + r;
        out[(size_t)row * N + col] = (f16)(acc[m][n][r] * s + sh);
      }
    }
  }
}

// ---------------- persistent LiGRU scan (one launch per layer) ----------------
// 128 wgs x 256 thr. wg owns j-cols [j0, j0+8). U slice in LDS f16.
// Shared per-step state (hpub, flags) uses relaxed AGENT-scope atomics only:
// write-through stores + coherence-point loads. No cache-wide fences.
// Ordering: __syncthreads() drains vmcnt(0) -> all write-through h stores are
// acked at the coherence point before tid0 issues the flag store.
__global__ __launch_bounds__(256) void k_scan(
    const float* __restrict__ U,   // (2048,1024) f32
    const f16* __restrict__ w,     // (16384,2048) f16 BN'd gates input
    f16* __restrict__ hpub,        // [2][32][1024] f16
    f16* __restrict__ xoutH,       // (16384,1024) f16 (if !last)
    float* __restrict__ xoutF,     // (16384,1024) f32 (if last)
    float* __restrict__ hh,        // (32,3,1024) f32
    unsigned* __restrict__ flags,  // [128][32] uints (128B stride per wg)
    int layer, int last, int nwg) {
  __shared__ f16 Ul[16 * 1024];
  __shared__ float gl[2][32][16];

  const int tid = threadIdx.x;
  const int lane = tid & 63, wid = tid >> 6;
  const int mt = wid & 1, kh = wid >> 1;
  const int j0 = blockIdx.x * 8;

  // stage U slice -> LDS (f32 -> f16)
  for (int i = tid; i < 16 * 1024; i += 256) {
    int e = i >> 10, k = i & 1023;
    int erow = (e < 8) ? (j0 + e) : (1024 + j0 + e - 8);
    Ul[((k >> 3) * 16 + e) * 8 + (k & 7)] = (f16)U[(size_t)erow * 1024 + k];
  }
  __syncthreads();

  const int cb = tid >> 3;  // combine: batch 0..31
  const int cj = tid & 7;   // combine: j 0..7
  float hreg = 0.f;         // exact f32 h for this thread's (cb, j0+cj)

  const int r16 = lane & 15, kg4 = lane >> 4;

  // prefetch w for t=0
  float wa = (float)w[(size_t)(cb * 512) * 2048 + j0 + cj];
  float wz = (float)w[(size_t)(cb * 512) * 2048 + 1024 + j0 + cj];

  for (int t = 0; t < 512; ++t) {
    const int cur = t & 1, nxt = cur ^ 1;

    // ---- matvec slice: gates[b, e_local] partial over this wave's k-half ----
    f32x4 acc = {};
    const f16* hbase = hpub + cur * 32768 + (size_t)(mt * 16 + r16) * 1024 + kh * 512 + kg4 * 8;
#pragma unroll
    for (int kk = 0; kk < 16; ++kk) {
      f16x8 a = ld_h(hbase + kk * 32);                      // coherent L3 read
      f16x8 b = LDF16X8(&Ul[((kh * 64 + kk * 4 + kg4) * 16 + r16) * 8]);
      acc = __builtin_amdgcn_mfma_f32_16x16x32_f16(a, b, acc, 0, 0, 0);
    }
#pragma unroll
    for (int r = 0; r < 4; ++r)
      gl[kh][mt * 16 + kg4 * 4 + r][r16] = acc[r];
    __syncthreads();

    // ---- combine: one (b,j) element per thread ----
    {
      float apre = gl[0][cb][cj] + gl[1][cb][cj] + wa;
      float zpre = gl[0][cb][8 + cj] + gl[1][cb][8 + cj] + wz;
      float z = 1.f / (1.f + expf(-zpre));
      float hn = z * hreg + (1.f - z) * fmaxf(apre, 0.f);
      hreg = hn;
      // pack 2 f16 per dword, agent-scope write-through store (even cj lanes)
      f16 hf = (f16)hn;
      unsigned hb = (unsigned)__builtin_bit_cast(unsigned short, hf);
      unsigned nb = __shfl_down(hb, 1, 64);
      if ((cj & 1) == 0)
        __hip_atomic_store((unsigned*)(hpub + nxt * 32768 + cb * 1024 + j0 + cj),
                           hb | (nb << 16), __ATOMIC_RELAXED, __HIP_MEMORY_SCOPE_AGENT);
      size_t xoff = (size_t)(cb * 512 + t) * 1024 + j0 + cj;
      if (last) xoutF[xoff] = hn;
      else      xoutH[xoff] = (f16)hn;
    }

    // ---- prefetch next step's w before the barrier ----
    if (t + 1 < 512) {
      size_t wrow = (size_t)(cb * 512 + t + 1) * 2048;
      wa = (float)w[wrow + j0 + cj];
      wz = (float)w[wrow + 1024 + j0 + cj];
    }

    // ---- flag grid barrier: relaxed agent atomics, no cache-wide ops ----
    __syncthreads();   // vmcnt(0) per wave: h stores acked at coherence point
    if (tid == 0)
      __hip_atomic_store(&flags[(size_t)blockIdx.x * 32], t + 1u,
                         __ATOMIC_RELAXED, __HIP_MEMORY_SCOPE_AGENT);
    if (tid < 64) {    // wave0: each lane polls 2 flags, both loads in flight
      const unsigned tgt = t + 1u;
      for (;;) {
        unsigned a = __hip_atomic_load(&flags[(size_t)tid * 32],
                                       __ATOMIC_RELAXED, __HIP_MEMORY_SCOPE_AGENT);
        unsigned b = __hip_atomic_load(&flags[(size_t)(64 + tid) * 32],
                                       __ATOMIC_RELAXED, __HIP_MEMORY_SCOPE_AGENT);
        if (a >= tgt && b >= tgt) break;
        __builtin_amdgcn_s_sleep(1);
      }
    }
    __syncthreads();
  }

  // final hidden state
  hh[(size_t)(cb * 3 + layer) * 1024 + j0 + cj] = hreg;
}

// ---------------- launcher ----------------
extern "C" void kernel_launch(void* const* d_in, const int* in_sizes, int n_in,
                              void* d_out, int out_size, void* d_ws, size_t ws_size,
                              hipStream_t stream) {
  const float* x     = (const float*)d_in[0];
  const float* W     = (const float*)d_in[1];
  const float* U     = (const float*)d_in[2];
  const float* gamma = (const float*)d_in[3];
  const float* beta  = (const float*)d_in[4];
  const float* rmean = (const float*)d_in[5];
  const float* rvar  = (const float*)d_in[6];
  float* outX  = (float*)d_out;                       // (32,512,1024) f32
  float* outHH = outX + (size_t)32 * 512 * 1024;      // (32,3,1024)  f32

  // Inter-layer f16 activations live in the d_out outX region (33.5 MB of 67 MB):
  // dead by the time the last layer's scan overwrites it with f32 output.
  f16* xb = (f16*)d_out;

  char* ws = (char*)d_ws;
  f16* wbuf = (f16*)(ws);                 // 16384*2048*2 = 67,108,864 B
  f16* Wb   = (f16*)(ws + 67108864);      //  2048*1024*2 =  4,194,304 B
  f16* hpub = (f16*)(ws + 71303168);      //  2*32*1024*2 =    131,072 B
  unsigned* flags = (unsigned*)(ws + 71434240);  // 128*32*4 = 16,384 B
  // total d_ws usage: ~71.5 MB

  // x -> f16
  k_cvt<<<16384, 256, 0, stream>>>(x, xb, 16777216);

  for (int l = 0; l < 3; ++l) {
    // W[l] -> f16
    k_cvt<<<2048, 256, 0, stream>>>(W + (size_t)l * 2097152, Wb, 2097152);
    // w = BN(x_l @ W^T)
    k_gemm_bn<<<dim3(128, 16), 256, 0, stream>>>(
        xb, Wb, gamma + l * 2048, beta + l * 2048, rmean + l * 2048, rvar + l * 2048,
        wbuf, 16384, 2048, 1024);
    // reset h and flags, then scan
    hipMemsetAsync(hpub, 0, 131072, stream);
    hipMemsetAsync(flags, 0, 16384, stream);
    k_scan<<<128, 256, 0, stream>>>(
        U + (size_t)l * 2097152, wbuf, hpub,
        xb, outX, outHH, flags, l, (l == 2) ? 1 : 0, 128);
  }
}